// Round 1
// baseline (3319.476 us; speedup 1.0000x reference)
//
#include <hip/hip_runtime.h>
#include <cstdint>
#include <cstddef>

// ---------------------------------------------------------------------------
// Round 6: move all large GEMMs (L0/L1 input projections, attention-u) from
// fp32 vector FMA (~33 TF effective) to bf16x3 split MFMA (Ah*Bh + Ah*Bl +
// Al*Bh, fp32-equivalent accuracy, ~833 TF logical peak). m97-structure:
// 128x128 tile, BK=32, 4 waves, global_load_lds(16B) staging, 2 barriers/step,
// 48 MFMA + 16 ds_read_b128 per K-step. Weights pre-split once; activations
// split by cheap elementwise kernels. lstm_rec3 / dot_v / attn_pool / head
// unchanged (verified).
// ---------------------------------------------------------------------------

constexpr int Bn   = 512;
constexpr int Cn   = 271;
constexpr int Tn   = 281;
constexpr int Hn   = 128;
constexpr int NCLS = 1854;
constexpr int Gn   = 4 * Hn;    // 512
constexpr int Kp0  = 288;       // layer-0 K (271) zero-padded to multiple of 32

typedef unsigned short u16;
typedef __attribute__((__ext_vector_type__(8))) short bf16x8;  // 8 bf16 (4 VGPR)
typedef __attribute__((__ext_vector_type__(4))) float f32x4;   // 4 f32 acc

#define DEVINL __device__ __forceinline__

DEVINL float sigm(float x)       { return 1.f / (1.f + __expf(-x)); }
DEVINL float tanhf_fast(float x) { return 2.f / (1.f + __expf(-2.f * x)) - 1.f; }

// split fp32 v into bf16 hi (truncated top 16 bits) + bf16 lo (exact residual,
// truncated). (hi+lo) represents v with rel err ~2^-17.
DEVINL void splitf(float v, u16& h, u16& l) {
  const uint32_t b = __float_as_uint(v);
  h = (u16)(b >> 16);
  const float lf = v - __uint_as_float(b & 0xFFFF0000u);
  l = (u16)(__float_as_uint(lf) >> 16);
}

#define GLL16(gp, lp) __builtin_amdgcn_global_load_lds(                        \
    (const __attribute__((address_space(1))) uint32_t*)(gp),                   \
    (__attribute__((address_space(3))) uint32_t*)(lp), 16, 0, 0)

// ---------------------------------------------------------------------------
// bf16x3 MFMA GEMM: C[m][n] = (act)( sum_k A(m,k)*B(n,k) + bias1 + bias2 )
// A: hi/lo bf16 [M][K], B: hi/lo bf16 [N][K], K % 32 == 0 (pre-padded).
// Tile 128x128, BK=32, 256 thr = 4 waves, wave tile 64x64 (4x4 16x16 frags).
// Staging: pure global_load_lds (16B); fragments: ds_read_b128; 48 MFMA/step.
// ---------------------------------------------------------------------------
template <int ACT, int NBIAS>
__global__ __launch_bounds__(256, 2) void gemm_mfma3(
    const u16* __restrict__ Ah, const u16* __restrict__ Al,
    const u16* __restrict__ Bh, const u16* __restrict__ Bl,
    const float* __restrict__ bias1, const float* __restrict__ bias2,
    float* __restrict__ Cout, int Mdim, int Ndim, int Kdim, int ldc)
{
  __shared__ __align__(16) u16 Ash[128][32];
  __shared__ __align__(16) u16 Asl[128][32];
  __shared__ __align__(16) u16 Bsh[128][32];
  __shared__ __align__(16) u16 Bsl[128][32];

  const int tid = threadIdx.x;
  const int w   = tid >> 6;        // wave 0..3
  const int l   = tid & 63;
  const int lr  = l & 15;          // fragment row/col within 16
  const int lg  = l >> 4;          // k-group 0..3
  const int row0 = blockIdx.x * 128;
  const int col0 = blockIdx.y * 128;
  const int mr = (w >> 1) * 64;    // wave M offset in tile
  const int nc = (w & 1) * 64;     // wave N offset in tile

  const f32x4 z4 = {0.f, 0.f, 0.f, 0.f};
  f32x4 acc[4][4];
#pragma unroll
  for (int m = 0; m < 4; m++)
#pragma unroll
    for (int n = 0; n < 4; n++) acc[m][n] = z4;

  // staging geometry: per wave, 2 issues of 16 rows (64B/row) per array.
  // lane l -> row (l>>2), u16-col (l&3)*8; LDS dest = uniform base + lane*16B.
  const int srow  = (l >> 2);      // 0..15 within 16-row stripe
  const int scol8 = (l & 3) * 8;   // u16 offset within 32-elem row

  for (int k0 = 0; k0 < Kdim; k0 += 32) {
#pragma unroll
    for (int i = 0; i < 2; i++) {
      const int lrow = w * 32 + i * 16;                       // LDS stripe base
      const int ra = min(row0 + lrow + srow, Mdim - 1);       // clamp (masked at epilogue)
      const int rb = min(col0 + lrow + srow, Ndim - 1);
      const size_t ao = (size_t)ra * Kdim + k0 + scol8;
      const size_t bo = (size_t)rb * Kdim + k0 + scol8;
      GLL16(Ah + ao, &Ash[lrow][0]);
      GLL16(Al + ao, &Asl[lrow][0]);
      GLL16(Bh + bo, &Bsh[lrow][0]);
      GLL16(Bl + bo, &Bsl[lrow][0]);
    }
    __syncthreads();   // compiler drains vmcnt(0) before s_barrier

    bf16x8 afh[4], afl[4], bfh[4], bfl[4];
#pragma unroll
    for (int m = 0; m < 4; m++) {
      afh[m] = *(const bf16x8*)&Ash[mr + m * 16 + lr][lg * 8];
      afl[m] = *(const bf16x8*)&Asl[mr + m * 16 + lr][lg * 8];
    }
#pragma unroll
    for (int n = 0; n < 4; n++) {
      bfh[n] = *(const bf16x8*)&Bsh[nc + n * 16 + lr][lg * 8];
      bfl[n] = *(const bf16x8*)&Bsl[nc + n * 16 + lr][lg * 8];
    }
#pragma unroll
    for (int m = 0; m < 4; m++)
#pragma unroll
      for (int n = 0; n < 4; n++) {
        acc[m][n] = __builtin_amdgcn_mfma_f32_16x16x32_bf16(afh[m], bfh[n], acc[m][n], 0, 0, 0);
        acc[m][n] = __builtin_amdgcn_mfma_f32_16x16x32_bf16(afh[m], bfl[n], acc[m][n], 0, 0, 0);
        acc[m][n] = __builtin_amdgcn_mfma_f32_16x16x32_bf16(afl[m], bfh[n], acc[m][n], 0, 0, 0);
      }
    __syncthreads();
  }

  // epilogue: C/D layout col = lane&15, row = (lane>>4)*4 + reg  [HW-verified]
#pragma unroll
  for (int n = 0; n < 4; n++) {
    const int gcol = col0 + nc + n * 16 + lr;
    if (gcol >= Ndim) continue;
    float bv = 0.f;
    if (NBIAS >= 1) bv += bias1[gcol];
    if (NBIAS >= 2) bv += bias2[gcol];
#pragma unroll
    for (int m = 0; m < 4; m++) {
#pragma unroll
      for (int r = 0; r < 4; r++) {
        const int grow = row0 + mr + m * 16 + lg * 4 + r;
        if (grow >= Mdim) continue;
        float v = acc[m][n][r] + bv;
        if (ACT == 1) v = tanhf_fast(v);
        Cout[(size_t)grow * ldc + gcol] = v;
      }
    }
  }
}

// ---------------------------------------------------------------------------
// generic fp32 -> bf16 hi/lo split with zero K-padding.
// TRANS=0: in [R][Kin] row-major. TRANS=1: in [Kin][R] (out[r][k]=in[k][r]).
// out hi/lo: [R][Kout]. block = 4 rows x 64 lanes.
// ---------------------------------------------------------------------------
template <int TRANS>
__global__ __launch_bounds__(256) void split_kernel(
    const float* __restrict__ in, u16* __restrict__ oh, u16* __restrict__ ol,
    int R, int Kin, int Kout)
{
  const int r = blockIdx.x * 4 + (threadIdx.x >> 6);
  if (r >= R) return;
  const int lane = threadIdx.x & 63;
  for (int k = lane * 4; k < Kout; k += 256) {
    float v[4];
#pragma unroll
    for (int j = 0; j < 4; j++) {
      const int kk = k + j;
      v[j] = (kk < Kin)
               ? (TRANS ? in[(size_t)kk * R + r] : in[(size_t)r * Kin + kk])
               : 0.f;
    }
    u16 hs[4], ls[4];
#pragma unroll
    for (int j = 0; j < 4; j++) splitf(v[j], hs[j], ls[j]);
    const size_t o = (size_t)r * Kout + k;
    *(ushort4*)&oh[o] = make_ushort4(hs[0], hs[1], hs[2], hs[3]);
    *(ushort4*)&ol[o] = make_ushort4(ls[0], ls[1], ls[2], ls[3]);
  }
}

// ---------------------------------------------------------------------------
// X transpose + split: X[b][c][t] fp32 -> xh/xl[b*Tn + t][Kp0] bf16 (k=c,
// zero-padded to 288). 32x32 LDS-tiled transpose, grid (9, 9, Bc).
// ---------------------------------------------------------------------------
__global__ __launch_bounds__(256) void xsplit_kernel(
    const float* __restrict__ X, u16* __restrict__ xh, u16* __restrict__ xl)
{
  __shared__ float tile[32][33];
  const int t0 = blockIdx.x * 32, c0 = blockIdx.y * 32, b = blockIdx.z;
  const int tx = threadIdx.x & 31, ty = threadIdx.x >> 5;   // ty: 8 c-rows
#pragma unroll
  for (int i = 0; i < 4; i++) {
    const int c = c0 + ty + i * 8, t = t0 + tx;
    float v = 0.f;
    if (c < Cn && t < Tn) v = X[((size_t)b * Cn + c) * Tn + t];
    tile[ty + i * 8][tx] = v;                               // tile[c'][t']
  }
  __syncthreads();
  const int tq = threadIdx.x >> 3;          // t' 0..31
  const int kq = (threadIdx.x & 7) * 4;     // k' quad 0..28
  const int t = t0 + tq;
  if (t >= Tn) return;
  u16 hs[4], ls[4];
#pragma unroll
  for (int j = 0; j < 4; j++) splitf(tile[kq + j][tq], hs[j], ls[j]);
  const size_t o = ((size_t)b * Tn + t) * Kp0 + c0 + kq;
  *(ushort4*)&xh[o] = make_ushort4(hs[0], hs[1], hs[2], hs[3]);
  *(ushort4*)&xl[o] = make_ushort4(ls[0], ls[1], ls[2], ls[3]);
}

// ---------------------------------------------------------------------------
// fp32 tiled GEMM (kept for head only). Same as round 5.
// ---------------------------------------------------------------------------
template <int AMODE, int BMODE, int ACT, int NBIAS>
__global__ __launch_bounds__(256) void gemm_tile(
    const float* __restrict__ A, const float* __restrict__ Bm,
    const float* __restrict__ bias1, const float* __restrict__ bias2,
    float* __restrict__ Cout, int Mdim, int Ndim, int Kdim, int ldc)
{
  __shared__ __align__(16) float As[8][128];
  __shared__ __align__(16) float Bs[8][128];

  const int tid  = threadIdx.x;
  const int tx   = tid & 15;
  const int ty   = tid >> 4;
  const int row0 = blockIdx.x * 128;
  const int col0 = blockIdx.y * 128;

  float acc[8][8];
#pragma unroll
  for (int i = 0; i < 8; i++)
#pragma unroll
    for (int j = 0; j < 8; j++) acc[i][j] = 0.f;

  for (int k0 = 0; k0 < Kdim; k0 += 8) {
    if (AMODE == 0) {
      const int q  = tid >> 7;
      const int r  = tid & 127;
      const int gr = row0 + r;
      const int gk = k0 + q * 4;
      float4 v = make_float4(0.f, 0.f, 0.f, 0.f);
      if (gr < Mdim && gk + 3 < Kdim)
        v = *(const float4*)&A[(size_t)gr * Kdim + gk];
      As[q * 4 + 0][r] = v.x;
      As[q * 4 + 1][r] = v.y;
      As[q * 4 + 2][r] = v.z;
      As[q * 4 + 3][r] = v.w;
    } else {
#pragma unroll
      for (int l = 0; l < 4; l++) {
        const int e  = tid + l * 256;
        const int r  = e & 127;
        const int kk = e >> 7;
        const int gr = row0 + r;
        const int gk = k0 + kk;
        float v = 0.f;
        if (gr < Mdim && gk < Kdim) {
          const int bb = gr / Tn;
          const int tt = gr - bb * Tn;
          v = A[((size_t)bb * Cn + gk) * Tn + tt];
        }
        As[kk][r] = v;
      }
    }
#pragma unroll
    for (int l = 0; l < 4; l++) {
      const int e = tid + l * 256;
      int kk, cc;
      if (BMODE == 0) { kk = e & 7;   cc = e >> 3; }
      else            { cc = e & 127; kk = e >> 7; }
      const int gn = col0 + cc;
      const int gk = k0 + kk;
      float v = 0.f;
      if (gn < Ndim && gk < Kdim)
        v = (BMODE == 0) ? Bm[(size_t)gn * Kdim + gk]
                         : Bm[(size_t)gk * Ndim + gn];
      Bs[kk][cc] = v;
    }
    __syncthreads();
#pragma unroll
    for (int kk = 0; kk < 8; kk++) {
      const float4 a0 = *(const float4*)&As[kk][ty * 8];
      const float4 a1 = *(const float4*)&As[kk][ty * 8 + 4];
      const float4 b0 = *(const float4*)&Bs[kk][tx * 8];
      const float4 b1 = *(const float4*)&Bs[kk][tx * 8 + 4];
      const float av[8] = {a0.x, a0.y, a0.z, a0.w, a1.x, a1.y, a1.z, a1.w};
      const float bv[8] = {b0.x, b0.y, b0.z, b0.w, b1.x, b1.y, b1.z, b1.w};
#pragma unroll
      for (int i = 0; i < 8; i++)
#pragma unroll
        for (int j = 0; j < 8; j++) acc[i][j] = fmaf(av[i], bv[j], acc[i][j]);
    }
    __syncthreads();
  }
#pragma unroll
  for (int i = 0; i < 8; i++) {
    const int gr = row0 + ty * 8 + i;
    if (gr >= Mdim) continue;
    const size_t rowoff = (size_t)gr * ldc;
#pragma unroll
    for (int j = 0; j < 8; j++) {
      const int gn = col0 + tx * 8 + j;
      if (gn >= Ndim) continue;
      float v = acc[i][j];
      if (NBIAS >= 1) v += bias1[gn];
      if (NBIAS >= 2) v += bias2[gn];
      if (ACT == 1) v = tanhf_fast(v);
      Cout[rowoff + gn] = v;
    }
  }
}

// ---------------------------------------------------------------------------
// LSTM recurrence v3 (round 5, unchanged/verified).
// ---------------------------------------------------------------------------
__global__ __launch_bounds__(512, 2) void lstm_rec3(
    const float* __restrict__ xw,
    const float* __restrict__ whhf,
    const float* __restrict__ whhb,
    float* __restrict__ hout, int MC)
{
  const int dir = blockIdx.y;
  const int row = blockIdx.x;
  const int n   = threadIdx.x;
  const int j   = n >> 2;
  const int q   = n & 3;
  const float* __restrict__ whh = dir ? whhb : whhf;
  const float* __restrict__ xwd = xw + (size_t)dir * MC * Gn;

  __shared__ __align__(16) float hl[2][140];

  float w[4][32];
#pragma unroll
  for (int g = 0; g < 4; g++) {
    const float4* wp = (const float4*)&whh[((size_t)(g * Hn + j)) * Hn + 32 * q];
#pragma unroll
    for (int i = 0; i < 8; i++) {
      const float4 v = wp[i];
      w[g][4 * i + 0] = v.x; w[g][4 * i + 1] = v.y;
      w[g][4 * i + 2] = v.z; w[g][4 * i + 3] = v.w;
    }
  }
  if (n < 140) hl[0][n] = 0.f;
  float c = 0.f;
  float hbuf[8];
  const size_t srow = (size_t)row * Tn;
  float* __restrict__ hop = hout + srow * 256 + dir * Hn + j;
  const int jpad = j + ((j >> 5) << 2);

  float xg = xwd[(srow + (dir ? (Tn - 1) : 0)) * Gn + q * Hn + j];
  __syncthreads();

  for (int s8 = 0; s8 < Tn - 1; s8 += 8) {
#pragma unroll
    for (int u = 0; u < 8; u++) {
      const int s = s8 + u;
      const int p = u & 1;
      const int tn_ = dir ? (Tn - 2 - s) : (s + 1);
      const float xgn = xwd[(srow + tn_) * Gn + q * Hn + j];
      float a0 = 0.f, a1 = 0.f, a2 = 0.f, a3 = 0.f;
      const float* hs = &hl[p][36 * q];
#pragma unroll
      for (int i = 0; i < 8; i++) {
        const float4 h4 = *(const float4*)&hs[4 * i];
        a0 = fmaf(w[0][4 * i + 0], h4.x, a0);
        a0 = fmaf(w[0][4 * i + 1], h4.y, a0);
        a0 = fmaf(w[0][4 * i + 2], h4.z, a0);
        a0 = fmaf(w[0][4 * i + 3], h4.w, a0);
        a1 = fmaf(w[1][4 * i + 0], h4.x, a1);
        a1 = fmaf(w[1][4 * i + 1], h4.y, a1);
        a1 = fmaf(w[1][4 * i + 2], h4.z, a1);
        a1 = fmaf(w[1][4 * i + 3], h4.w, a1);
        a2 = fmaf(w[2][4 * i + 0], h4.x, a2);
        a2 = fmaf(w[2][4 * i + 1], h4.y, a2);
        a2 = fmaf(w[2][4 * i + 2], h4.z, a2);
        a2 = fmaf(w[2][4 * i + 3], h4.w, a2);
        a3 = fmaf(w[3][4 * i + 0], h4.x, a3);
        a3 = fmaf(w[3][4 * i + 1], h4.y, a3);
        a3 = fmaf(w[3][4 * i + 2], h4.z, a3);
        a3 = fmaf(w[3][4 * i + 3], h4.w, a3);
      }
      a0 += (q == 0) ? xg : 0.f;
      a1 += (q == 1) ? xg : 0.f;
      a2 += (q == 2) ? xg : 0.f;
      a3 += (q == 3) ? xg : 0.f;
      a0 += __shfl_xor(a0, 1); a0 += __shfl_xor(a0, 2);
      a1 += __shfl_xor(a1, 1); a1 += __shfl_xor(a1, 2);
      a2 += __shfl_xor(a2, 1); a2 += __shfl_xor(a2, 2);
      a3 += __shfl_xor(a3, 1); a3 += __shfl_xor(a3, 2);
      const float iv = sigm(a0);
      const float fv = sigm(a1);
      const float gv = tanhf_fast(a2);
      const float ov = sigm(a3);
      c = fv * c + iv * gv;
      const float hv = ov * tanhf_fast(c);
      if (q == 0) hl[p ^ 1][jpad] = hv;
      hbuf[u] = hv;
      __syncthreads();
      xg = xgn;
    }
    if (q == 0) {
#pragma unroll
      for (int u = 0; u < 8; u++) {
        const int ss = s8 + u;
        const int tt = dir ? (Tn - 1 - ss) : ss;
        hop[(size_t)tt * 256] = hbuf[u];
      }
    }
  }
  {
    float a0 = 0.f, a1 = 0.f, a2 = 0.f, a3 = 0.f;
    const float* hs = &hl[0][36 * q];
#pragma unroll
    for (int i = 0; i < 8; i++) {
      const float4 h4 = *(const float4*)&hs[4 * i];
      a0 = fmaf(w[0][4 * i + 0], h4.x, a0);
      a0 = fmaf(w[0][4 * i + 1], h4.y, a0);
      a0 = fmaf(w[0][4 * i + 2], h4.z, a0);
      a0 = fmaf(w[0][4 * i + 3], h4.w, a0);
      a1 = fmaf(w[1][4 * i + 0], h4.x, a1);
      a1 = fmaf(w[1][4 * i + 1], h4.y, a1);
      a1 = fmaf(w[1][4 * i + 2], h4.z, a1);
      a1 = fmaf(w[1][4 * i + 3], h4.w, a1);
      a2 = fmaf(w[2][4 * i + 0], h4.x, a2);
      a2 = fmaf(w[2][4 * i + 1], h4.y, a2);
      a2 = fmaf(w[2][4 * i + 2], h4.z, a2);
      a2 = fmaf(w[2][4 * i + 3], h4.w, a2);
      a3 = fmaf(w[3][4 * i + 0], h4.x, a3);
      a3 = fmaf(w[3][4 * i + 1], h4.y, a3);
      a3 = fmaf(w[3][4 * i + 2], h4.z, a3);
      a3 = fmaf(w[3][4 * i + 3], h4.w, a3);
    }
    a0 += (q == 0) ? xg : 0.f;
    a1 += (q == 1) ? xg : 0.f;
    a2 += (q == 2) ? xg : 0.f;
    a3 += (q == 3) ? xg : 0.f;
    a0 += __shfl_xor(a0, 1); a0 += __shfl_xor(a0, 2);
    a1 += __shfl_xor(a1, 1); a1 += __shfl_xor(a1, 2);
    a2 += __shfl_xor(a2, 1); a2 += __shfl_xor(a2, 2);
    a3 += __shfl_xor(a3, 1); a3 += __shfl_xor(a3, 2);
    const float iv = sigm(a0);
    const float fv = sigm(a1);
    const float gv = tanhf_fast(a2);
    const float ov = sigm(a3);
    c = fv * c + iv * gv;
    const float hv = ov * tanhf_fast(c);
    if (q == 0) {
      const int tt = dir ? 0 : (Tn - 1);
      hop[(size_t)tt * 256] = hv;
    }
  }
}

// ---------------------------------------------------------------------------
__global__ __launch_bounds__(256) void dot_v_kernel(
    const float* __restrict__ u, const float* __restrict__ v,
    float* __restrict__ a, int MC)
{
  const int lane = threadIdx.x & 63;
  const int row  = blockIdx.x * 4 + (threadIdx.x >> 6);
  if (row >= MC) return;
  const float4 uv = ((const float4*)(u + (size_t)row * 256))[lane];
  const float4 vv = ((const float4*)v)[lane];
  float p = uv.x * vv.x + uv.y * vv.y + uv.z * vv.z + uv.w * vv.w;
#pragma unroll
  for (int off = 32; off > 0; off >>= 1) p += __shfl_down(p, off);
  if (lane == 0) a[row] = p;
}

// ---------------------------------------------------------------------------
__global__ __launch_bounds__(256) void attn_pool(
    const float* __restrict__ a, const float* __restrict__ h1,
    float* __restrict__ wout)
{
  const int b    = blockIdx.x;
  const int tid  = threadIdx.x;
  const int lane = tid & 63;
  const int wid  = tid >> 6;
  __shared__ float sa[Tn];
  __shared__ float red[8];

  float lmax = -3.4e38f;
  for (int t = tid; t < Tn; t += 256) {
    const float x = a[(size_t)b * Tn + t];
    sa[t] = x;
    lmax  = fmaxf(lmax, x);
  }
#pragma unroll
  for (int off = 1; off < 64; off <<= 1) lmax = fmaxf(lmax, __shfl_xor(lmax, off));
  if (lane == 0) red[wid] = lmax;
  __syncthreads();
  const float bmax = fmaxf(fmaxf(red[0], red[1]), fmaxf(red[2], red[3]));

  float lsum = 0.f;
  for (int t = tid; t < Tn; t += 256) {
    const float e = __expf(sa[t] - bmax);
    sa[t] = e;
    lsum += e;
  }
#pragma unroll
  for (int off = 1; off < 64; off <<= 1) lsum += __shfl_xor(lsum, off);
  if (lane == 0) red[4 + wid] = lsum;
  __syncthreads();
  const float inv = 1.f / (red[4] + red[5] + red[6] + red[7]);

  float acc = 0.f;
  const float* hb = h1 + (size_t)b * Tn * 256 + tid;
  for (int t = 0; t < Tn; t++) acc += sa[t] * hb[(size_t)t * 256];
  wout[(size_t)b * 256 + tid] = acc * inv;
}

// ---------------------------------------------------------------------------
extern "C" void kernel_launch(void* const* d_in, const int* in_sizes, int n_in,
                              void* d_out, int out_size, void* d_ws, size_t ws_size,
                              hipStream_t stream)
{
  const float* X      = (const float*)d_in[0];
  const float* w_ih0f = (const float*)d_in[1];
  const float* w_hh0f = (const float*)d_in[2];
  const float* b_ih0f = (const float*)d_in[3];
  const float* b_hh0f = (const float*)d_in[4];
  const float* w_ih0b = (const float*)d_in[5];
  const float* w_hh0b = (const float*)d_in[6];
  const float* b_ih0b = (const float*)d_in[7];
  const float* b_hh0b = (const float*)d_in[8];
  const float* w_ih1f = (const float*)d_in[9];
  const float* w_hh1f = (const float*)d_in[10];
  const float* b_ih1f = (const float*)d_in[11];
  const float* b_hh1f = (const float*)d_in[12];
  const float* w_ih1b = (const float*)d_in[13];
  const float* w_hh1b = (const float*)d_in[14];
  const float* b_ih1b = (const float*)d_in[15];
  const float* b_hh1b = (const float*)d_in[16];
  const float* att_W  = (const float*)d_in[17];
  const float* att_v  = (const float*)d_in[18];
  const float* head_W = (const float*)d_in[19];
  const float* head_b = (const float*)d_in[20];

  auto al256 = [](size_t x) { return (x + 255) & ~(size_t)255; };

  // footprint for chunk rows mc:
  //   wgt + weight-splits + xwc(2*mc*512 f32) + h0c + h1c + ac + act-region
  auto need_for = [&](size_t mc) -> size_t {
    size_t s = 0;
    s += al256((size_t)512 * 256 * 4);                 // wgt
    s += 4 * al256((size_t)512 * Kp0 * 2);             // w0 f/b hi/lo
    s += 4 * al256((size_t)512 * 256 * 2);             // w1 f/b hi/lo
    s += 2 * al256((size_t)256 * 256 * 2);             // att_W^T hi/lo
    s += al256(2 * mc * (size_t)Gn * 4);               // xwc
    s += al256(mc * 256 * 4);                          // h0c
    s += al256(mc * 256 * 4);                          // h1c
    s += al256(mc * 4);                                // ac
    s += al256(2 * mc * (size_t)Kp0 * 2);              // act split region
    return s;
  };

  int Bc = 8;
  {
    const int cands[7] = {512, 256, 128, 64, 32, 16, 8};
    for (int i = 0; i < 7; i++) {
      if (need_for((size_t)cands[i] * Tn) <= ws_size) { Bc = cands[i]; break; }
    }
  }
  const size_t MCs = (size_t)Bc * Tn;
  const int    MC  = (int)MCs;

  char* p = (char*)d_ws;
  float* wgt  = (float*)p;  p += al256((size_t)512 * 256 * 4);
  u16* w0fh = (u16*)p;      p += al256((size_t)512 * Kp0 * 2);
  u16* w0fl = (u16*)p;      p += al256((size_t)512 * Kp0 * 2);
  u16* w0bh = (u16*)p;      p += al256((size_t)512 * Kp0 * 2);
  u16* w0bl = (u16*)p;      p += al256((size_t)512 * Kp0 * 2);
  u16* w1fh = (u16*)p;      p += al256((size_t)512 * 256 * 2);
  u16* w1fl = (u16*)p;      p += al256((size_t)512 * 256 * 2);
  u16* w1bh = (u16*)p;      p += al256((size_t)512 * 256 * 2);
  u16* w1bl = (u16*)p;      p += al256((size_t)512 * 256 * 2);
  u16* aWh  = (u16*)p;      p += al256((size_t)256 * 256 * 2);
  u16* aWl  = (u16*)p;      p += al256((size_t)256 * 256 * 2);
  float* xwc = (float*)p;   p += al256(2 * MCs * (size_t)Gn * 4);
  float* h0c = (float*)p;   p += al256(MCs * 256 * 4);
  float* h1c = (float*)p;   p += al256(MCs * 256 * 4);
  float* ac  = (float*)p;   p += al256(MCs * 4);
  u16* act_h = (u16*)p;
  u16* act_l = (u16*)(p + MCs * (size_t)Kp0 * 2);      // lo half of act region
  float* u   = xwc;                                    // reuse (xw dead by phase 5)

  const dim3 blk(256);
  const int  mt  = (MC + 127) / 128;
  const int  nch = Bn / Bc;

  // one-time weight splits (K zero-padded to /32; att_W transposed to [N][K])
  split_kernel<0><<<dim3(128), blk, 0, stream>>>(w_ih0f, w0fh, w0fl, 512, Cn, Kp0);
  split_kernel<0><<<dim3(128), blk, 0, stream>>>(w_ih0b, w0bh, w0bl, 512, Cn, Kp0);
  split_kernel<0><<<dim3(128), blk, 0, stream>>>(w_ih1f, w1fh, w1fl, 512, 256, 256);
  split_kernel<0><<<dim3(128), blk, 0, stream>>>(w_ih1b, w1bh, w1bl, 512, 256, 256);
  split_kernel<1><<<dim3(64),  blk, 0, stream>>>(att_W,  aWh,  aWl,  256, 256, 256);

  for (int ch = 0; ch < nch; ch++) {
    const float* Xc   = X + (size_t)ch * Bc * Cn * Tn;
    float*       wgtc = wgt + (size_t)ch * Bc * 256;

    // 0) transpose+split X chunk -> act (bf16 hi/lo, [MC][288])
    xsplit_kernel<<<dim3(9, 9, Bc), blk, 0, stream>>>(Xc, act_h, act_l);
    // 1) layer-0 input projections (MFMA bf16x3), both biases folded
    gemm_mfma3<0, 2><<<dim3(mt, 4), blk, 0, stream>>>(
        act_h, act_l, w0fh, w0fl, b_ih0f, b_hh0f, xwc, MC, Gn, Kp0, Gn);
    gemm_mfma3<0, 2><<<dim3(mt, 4), blk, 0, stream>>>(
        act_h, act_l, w0bh, w0bl, b_ih0b, b_hh0b, xwc + MCs * Gn, MC, Gn, Kp0, Gn);
    // 2) layer-0 recurrence
    lstm_rec3<<<dim3(Bc, 2), dim3(512), 0, stream>>>(xwc, w_hh0f, w_hh0b, h0c, MC);
    // 2.5) split h0 -> act (Xs dead)
    split_kernel<0><<<dim3((MC + 3) / 4), blk, 0, stream>>>(h0c, act_h, act_l, MC, 256, 256);
    // 3) layer-1 input projections
    gemm_mfma3<0, 2><<<dim3(mt, 4), blk, 0, stream>>>(
        act_h, act_l, w1fh, w1fl, b_ih1f, b_hh1f, xwc, MC, Gn, 256, Gn);
    gemm_mfma3<0, 2><<<dim3(mt, 4), blk, 0, stream>>>(
        act_h, act_l, w1bh, w1bl, b_ih1b, b_hh1b, xwc + MCs * Gn, MC, Gn, 256, Gn);
    // 4) layer-1 recurrence
    lstm_rec3<<<dim3(Bc, 2), dim3(512), 0, stream>>>(xwc, w_hh1f, w_hh1b, h1c, MC);
    // 4.5) split h1 -> act (h0s dead)
    split_kernel<0><<<dim3((MC + 3) / 4), blk, 0, stream>>>(h1c, act_h, act_l, MC, 256, 256);
    // 5) u = tanh(h1 @ att_W)
    gemm_mfma3<1, 0><<<dim3(mt, 2), blk, 0, stream>>>(
        act_h, act_l, aWh, aWl, nullptr, nullptr, u, MC, 256, 256, 256);
    // 6) a = u . att_v
    dot_v_kernel<<<dim3((MC + 3) / 4), blk, 0, stream>>>(u, att_v, ac, MC);
    // 7) softmax + pooling into this chunk's wgt slice
    attn_pool<<<dim3(Bc), blk, 0, stream>>>(ac, h1c, wgtc);
  }
  // 8) head (fp32, negligible: 0.5 GFLOP)
  gemm_tile<0, 0, 0, 1><<<dim3((Bn + 127) / 128, (NCLS + 127) / 128), blk, 0, stream>>>(
      wgt, head_W, head_b, nullptr, (float*)d_out, Bn, NCLS, 256, NCLS);
}

// Round 2
// 3285.300 us; speedup vs baseline: 1.0104x; 1.0104x over previous
//
#include <hip/hip_runtime.h>
#include <cstdint>
#include <cstddef>

// ---------------------------------------------------------------------------
// Round 7: single targeted change vs round 6.
//  * lstm_rec3: __launch_bounds__(512, 2) -> (512, 1). The "2" forced a
//    128-VGPR cap (16 waves/CU), which demoted the per-thread w[4][32]
//    (128 floats) weight array to memory: VGPR_Count=84, ~256KB/block/step
//    re-read through L2 (~18.9 GB/dispatch at ~36 TB/s = the measured
//    ~560 us). Occupancy counter shows only 1 block/CU was resident anyway
//    (23% ~= 8 waves), so (512,1) loses nothing and raises the cap to 256
//    VGPRs -> weights truly in registers.
// Everything else identical to round 6 (verified: passed, absmax 4.9e-4).
// ---------------------------------------------------------------------------

constexpr int Bn   = 512;
constexpr int Cn   = 271;
constexpr int Tn   = 281;
constexpr int Hn   = 128;
constexpr int NCLS = 1854;
constexpr int Gn   = 4 * Hn;    // 512
constexpr int Kp0  = 288;       // layer-0 K (271) zero-padded to multiple of 32

typedef unsigned short u16;
typedef __attribute__((__ext_vector_type__(8))) short bf16x8;  // 8 bf16 (4 VGPR)
typedef __attribute__((__ext_vector_type__(4))) float f32x4;   // 4 f32 acc

#define DEVINL __device__ __forceinline__

DEVINL float sigm(float x)       { return 1.f / (1.f + __expf(-x)); }
DEVINL float tanhf_fast(float x) { return 2.f / (1.f + __expf(-2.f * x)) - 1.f; }

// split fp32 v into bf16 hi (truncated top 16 bits) + bf16 lo (exact residual,
// truncated). (hi+lo) represents v with rel err ~2^-17.
DEVINL void splitf(float v, u16& h, u16& l) {
  const uint32_t b = __float_as_uint(v);
  h = (u16)(b >> 16);
  const float lf = v - __uint_as_float(b & 0xFFFF0000u);
  l = (u16)(__float_as_uint(lf) >> 16);
}

#define GLL16(gp, lp) __builtin_amdgcn_global_load_lds(                        \
    (const __attribute__((address_space(1))) uint32_t*)(gp),                   \
    (__attribute__((address_space(3))) uint32_t*)(lp), 16, 0, 0)

// ---------------------------------------------------------------------------
// bf16x3 MFMA GEMM: C[m][n] = (act)( sum_k A(m,k)*B(n,k) + bias1 + bias2 )
// A: hi/lo bf16 [M][K], B: hi/lo bf16 [N][K], K % 32 == 0 (pre-padded).
// Tile 128x128, BK=32, 256 thr = 4 waves, wave tile 64x64 (4x4 16x16 frags).
// Staging: pure global_load_lds (16B); fragments: ds_read_b128; 48 MFMA/step.
// ---------------------------------------------------------------------------
template <int ACT, int NBIAS>
__global__ __launch_bounds__(256, 2) void gemm_mfma3(
    const u16* __restrict__ Ah, const u16* __restrict__ Al,
    const u16* __restrict__ Bh, const u16* __restrict__ Bl,
    const float* __restrict__ bias1, const float* __restrict__ bias2,
    float* __restrict__ Cout, int Mdim, int Ndim, int Kdim, int ldc)
{
  __shared__ __align__(16) u16 Ash[128][32];
  __shared__ __align__(16) u16 Asl[128][32];
  __shared__ __align__(16) u16 Bsh[128][32];
  __shared__ __align__(16) u16 Bsl[128][32];

  const int tid = threadIdx.x;
  const int w   = tid >> 6;        // wave 0..3
  const int l   = tid & 63;
  const int lr  = l & 15;          // fragment row/col within 16
  const int lg  = l >> 4;          // k-group 0..3
  const int row0 = blockIdx.x * 128;
  const int col0 = blockIdx.y * 128;
  const int mr = (w >> 1) * 64;    // wave M offset in tile
  const int nc = (w & 1) * 64;     // wave N offset in tile

  const f32x4 z4 = {0.f, 0.f, 0.f, 0.f};
  f32x4 acc[4][4];
#pragma unroll
  for (int m = 0; m < 4; m++)
#pragma unroll
    for (int n = 0; n < 4; n++) acc[m][n] = z4;

  // staging geometry: per wave, 2 issues of 16 rows (64B/row) per array.
  // lane l -> row (l>>2), u16-col (l&3)*8; LDS dest = uniform base + lane*16B.
  const int srow  = (l >> 2);      // 0..15 within 16-row stripe
  const int scol8 = (l & 3) * 8;   // u16 offset within 32-elem row

  for (int k0 = 0; k0 < Kdim; k0 += 32) {
#pragma unroll
    for (int i = 0; i < 2; i++) {
      const int lrow = w * 32 + i * 16;                       // LDS stripe base
      const int ra = min(row0 + lrow + srow, Mdim - 1);       // clamp (masked at epilogue)
      const int rb = min(col0 + lrow + srow, Ndim - 1);
      const size_t ao = (size_t)ra * Kdim + k0 + scol8;
      const size_t bo = (size_t)rb * Kdim + k0 + scol8;
      GLL16(Ah + ao, &Ash[lrow][0]);
      GLL16(Al + ao, &Asl[lrow][0]);
      GLL16(Bh + bo, &Bsh[lrow][0]);
      GLL16(Bl + bo, &Bsl[lrow][0]);
    }
    __syncthreads();   // compiler drains vmcnt(0) before s_barrier

    bf16x8 afh[4], afl[4], bfh[4], bfl[4];
#pragma unroll
    for (int m = 0; m < 4; m++) {
      afh[m] = *(const bf16x8*)&Ash[mr + m * 16 + lr][lg * 8];
      afl[m] = *(const bf16x8*)&Asl[mr + m * 16 + lr][lg * 8];
    }
#pragma unroll
    for (int n = 0; n < 4; n++) {
      bfh[n] = *(const bf16x8*)&Bsh[nc + n * 16 + lr][lg * 8];
      bfl[n] = *(const bf16x8*)&Bsl[nc + n * 16 + lr][lg * 8];
    }
#pragma unroll
    for (int m = 0; m < 4; m++)
#pragma unroll
      for (int n = 0; n < 4; n++) {
        acc[m][n] = __builtin_amdgcn_mfma_f32_16x16x32_bf16(afh[m], bfh[n], acc[m][n], 0, 0, 0);
        acc[m][n] = __builtin_amdgcn_mfma_f32_16x16x32_bf16(afh[m], bfl[n], acc[m][n], 0, 0, 0);
        acc[m][n] = __builtin_amdgcn_mfma_f32_16x16x32_bf16(afl[m], bfh[n], acc[m][n], 0, 0, 0);
      }
    __syncthreads();
  }

  // epilogue: C/D layout col = lane&15, row = (lane>>4)*4 + reg  [HW-verified]
#pragma unroll
  for (int n = 0; n < 4; n++) {
    const int gcol = col0 + nc + n * 16 + lr;
    if (gcol >= Ndim) continue;
    float bv = 0.f;
    if (NBIAS >= 1) bv += bias1[gcol];
    if (NBIAS >= 2) bv += bias2[gcol];
#pragma unroll
    for (int m = 0; m < 4; m++) {
#pragma unroll
      for (int r = 0; r < 4; r++) {
        const int grow = row0 + mr + m * 16 + lg * 4 + r;
        if (grow >= Mdim) continue;
        float v = acc[m][n][r] + bv;
        if (ACT == 1) v = tanhf_fast(v);
        Cout[(size_t)grow * ldc + gcol] = v;
      }
    }
  }
}

// ---------------------------------------------------------------------------
// generic fp32 -> bf16 hi/lo split with zero K-padding.
// TRANS=0: in [R][Kin] row-major. TRANS=1: in [Kin][R] (out[r][k]=in[k][r]).
// out hi/lo: [R][Kout]. block = 4 rows x 64 lanes.
// ---------------------------------------------------------------------------
template <int TRANS>
__global__ __launch_bounds__(256) void split_kernel(
    const float* __restrict__ in, u16* __restrict__ oh, u16* __restrict__ ol,
    int R, int Kin, int Kout)
{
  const int r = blockIdx.x * 4 + (threadIdx.x >> 6);
  if (r >= R) return;
  const int lane = threadIdx.x & 63;
  for (int k = lane * 4; k < Kout; k += 256) {
    float v[4];
#pragma unroll
    for (int j = 0; j < 4; j++) {
      const int kk = k + j;
      v[j] = (kk < Kin)
               ? (TRANS ? in[(size_t)kk * R + r] : in[(size_t)r * Kin + kk])
               : 0.f;
    }
    u16 hs[4], ls[4];
#pragma unroll
    for (int j = 0; j < 4; j++) splitf(v[j], hs[j], ls[j]);
    const size_t o = (size_t)r * Kout + k;
    *(ushort4*)&oh[o] = make_ushort4(hs[0], hs[1], hs[2], hs[3]);
    *(ushort4*)&ol[o] = make_ushort4(ls[0], ls[1], ls[2], ls[3]);
  }
}

// ---------------------------------------------------------------------------
// X transpose + split: X[b][c][t] fp32 -> xh/xl[b*Tn + t][Kp0] bf16 (k=c,
// zero-padded to 288). 32x32 LDS-tiled transpose, grid (9, 9, Bc).
// ---------------------------------------------------------------------------
__global__ __launch_bounds__(256) void xsplit_kernel(
    const float* __restrict__ X, u16* __restrict__ xh, u16* __restrict__ xl)
{
  __shared__ float tile[32][33];
  const int t0 = blockIdx.x * 32, c0 = blockIdx.y * 32, b = blockIdx.z;
  const int tx = threadIdx.x & 31, ty = threadIdx.x >> 5;   // ty: 8 c-rows
#pragma unroll
  for (int i = 0; i < 4; i++) {
    const int c = c0 + ty + i * 8, t = t0 + tx;
    float v = 0.f;
    if (c < Cn && t < Tn) v = X[((size_t)b * Cn + c) * Tn + t];
    tile[ty + i * 8][tx] = v;                               // tile[c'][t']
  }
  __syncthreads();
  const int tq = threadIdx.x >> 3;          // t' 0..31
  const int kq = (threadIdx.x & 7) * 4;     // k' quad 0..28
  const int t = t0 + tq;
  if (t >= Tn) return;
  u16 hs[4], ls[4];
#pragma unroll
  for (int j = 0; j < 4; j++) splitf(tile[kq + j][tq], hs[j], ls[j]);
  const size_t o = ((size_t)b * Tn + t) * Kp0 + c0 + kq;
  *(ushort4*)&xh[o] = make_ushort4(hs[0], hs[1], hs[2], hs[3]);
  *(ushort4*)&xl[o] = make_ushort4(ls[0], ls[1], ls[2], ls[3]);
}

// ---------------------------------------------------------------------------
// fp32 tiled GEMM (kept for head only). Same as round 5.
// ---------------------------------------------------------------------------
template <int AMODE, int BMODE, int ACT, int NBIAS>
__global__ __launch_bounds__(256) void gemm_tile(
    const float* __restrict__ A, const float* __restrict__ Bm,
    const float* __restrict__ bias1, const float* __restrict__ bias2,
    float* __restrict__ Cout, int Mdim, int Ndim, int Kdim, int ldc)
{
  __shared__ __align__(16) float As[8][128];
  __shared__ __align__(16) float Bs[8][128];

  const int tid  = threadIdx.x;
  const int tx   = tid & 15;
  const int ty   = tid >> 4;
  const int row0 = blockIdx.x * 128;
  const int col0 = blockIdx.y * 128;

  float acc[8][8];
#pragma unroll
  for (int i = 0; i < 8; i++)
#pragma unroll
    for (int j = 0; j < 8; j++) acc[i][j] = 0.f;

  for (int k0 = 0; k0 < Kdim; k0 += 8) {
    if (AMODE == 0) {
      const int q  = tid >> 7;
      const int r  = tid & 127;
      const int gr = row0 + r;
      const int gk = k0 + q * 4;
      float4 v = make_float4(0.f, 0.f, 0.f, 0.f);
      if (gr < Mdim && gk + 3 < Kdim)
        v = *(const float4*)&A[(size_t)gr * Kdim + gk];
      As[q * 4 + 0][r] = v.x;
      As[q * 4 + 1][r] = v.y;
      As[q * 4 + 2][r] = v.z;
      As[q * 4 + 3][r] = v.w;
    } else {
#pragma unroll
      for (int l = 0; l < 4; l++) {
        const int e  = tid + l * 256;
        const int r  = e & 127;
        const int kk = e >> 7;
        const int gr = row0 + r;
        const int gk = k0 + kk;
        float v = 0.f;
        if (gr < Mdim && gk < Kdim) {
          const int bb = gr / Tn;
          const int tt = gr - bb * Tn;
          v = A[((size_t)bb * Cn + gk) * Tn + tt];
        }
        As[kk][r] = v;
      }
    }
#pragma unroll
    for (int l = 0; l < 4; l++) {
      const int e = tid + l * 256;
      int kk, cc;
      if (BMODE == 0) { kk = e & 7;   cc = e >> 3; }
      else            { cc = e & 127; kk = e >> 7; }
      const int gn = col0 + cc;
      const int gk = k0 + kk;
      float v = 0.f;
      if (gn < Ndim && gk < Kdim)
        v = (BMODE == 0) ? Bm[(size_t)gn * Kdim + gk]
                         : Bm[(size_t)gk * Ndim + gn];
      Bs[kk][cc] = v;
    }
    __syncthreads();
#pragma unroll
    for (int kk = 0; kk < 8; kk++) {
      const float4 a0 = *(const float4*)&As[kk][ty * 8];
      const float4 a1 = *(const float4*)&As[kk][ty * 8 + 4];
      const float4 b0 = *(const float4*)&Bs[kk][tx * 8];
      const float4 b1 = *(const float4*)&Bs[kk][tx * 8 + 4];
      const float av[8] = {a0.x, a0.y, a0.z, a0.w, a1.x, a1.y, a1.z, a1.w};
      const float bv[8] = {b0.x, b0.y, b0.z, b0.w, b1.x, b1.y, b1.z, b1.w};
#pragma unroll
      for (int i = 0; i < 8; i++)
#pragma unroll
        for (int j = 0; j < 8; j++) acc[i][j] = fmaf(av[i], bv[j], acc[i][j]);
    }
    __syncthreads();
  }
#pragma unroll
  for (int i = 0; i < 8; i++) {
    const int gr = row0 + ty * 8 + i;
    if (gr >= Mdim) continue;
    const size_t rowoff = (size_t)gr * ldc;
#pragma unroll
    for (int j = 0; j < 8; j++) {
      const int gn = col0 + tx * 8 + j;
      if (gn >= Ndim) continue;
      float v = acc[i][j];
      if (NBIAS >= 1) v += bias1[gn];
      if (NBIAS >= 2) v += bias2[gn];
      if (ACT == 1) v = tanhf_fast(v);
      Cout[rowoff + gn] = v;
    }
  }
}

// ---------------------------------------------------------------------------
// LSTM recurrence v4: identical math to v3; launch bounds (512,1) so the
// per-thread w[4][32] weight array (128 floats) fits the 256-VGPR cap.
// ---------------------------------------------------------------------------
__global__ __launch_bounds__(512, 1) void lstm_rec3(
    const float* __restrict__ xw,
    const float* __restrict__ whhf,
    const float* __restrict__ whhb,
    float* __restrict__ hout, int MC)
{
  const int dir = blockIdx.y;
  const int row = blockIdx.x;
  const int n   = threadIdx.x;
  const int j   = n >> 2;
  const int q   = n & 3;
  const float* __restrict__ whh = dir ? whhb : whhf;
  const float* __restrict__ xwd = xw + (size_t)dir * MC * Gn;

  __shared__ __align__(16) float hl[2][140];

  float w[4][32];
#pragma unroll
  for (int g = 0; g < 4; g++) {
    const float4* wp = (const float4*)&whh[((size_t)(g * Hn + j)) * Hn + 32 * q];
#pragma unroll
    for (int i = 0; i < 8; i++) {
      const float4 v = wp[i];
      w[g][4 * i + 0] = v.x; w[g][4 * i + 1] = v.y;
      w[g][4 * i + 2] = v.z; w[g][4 * i + 3] = v.w;
    }
  }
  if (n < 140) hl[0][n] = 0.f;
  float c = 0.f;
  float hbuf[8];
  const size_t srow = (size_t)row * Tn;
  float* __restrict__ hop = hout + srow * 256 + dir * Hn + j;
  const int jpad = j + ((j >> 5) << 2);

  float xg = xwd[(srow + (dir ? (Tn - 1) : 0)) * Gn + q * Hn + j];
  __syncthreads();

  for (int s8 = 0; s8 < Tn - 1; s8 += 8) {
#pragma unroll
    for (int u = 0; u < 8; u++) {
      const int s = s8 + u;
      const int p = u & 1;
      const int tn_ = dir ? (Tn - 2 - s) : (s + 1);
      const float xgn = xwd[(srow + tn_) * Gn + q * Hn + j];
      float a0 = 0.f, a1 = 0.f, a2 = 0.f, a3 = 0.f;
      const float* hs = &hl[p][36 * q];
#pragma unroll
      for (int i = 0; i < 8; i++) {
        const float4 h4 = *(const float4*)&hs[4 * i];
        a0 = fmaf(w[0][4 * i + 0], h4.x, a0);
        a0 = fmaf(w[0][4 * i + 1], h4.y, a0);
        a0 = fmaf(w[0][4 * i + 2], h4.z, a0);
        a0 = fmaf(w[0][4 * i + 3], h4.w, a0);
        a1 = fmaf(w[1][4 * i + 0], h4.x, a1);
        a1 = fmaf(w[1][4 * i + 1], h4.y, a1);
        a1 = fmaf(w[1][4 * i + 2], h4.z, a1);
        a1 = fmaf(w[1][4 * i + 3], h4.w, a1);
        a2 = fmaf(w[2][4 * i + 0], h4.x, a2);
        a2 = fmaf(w[2][4 * i + 1], h4.y, a2);
        a2 = fmaf(w[2][4 * i + 2], h4.z, a2);
        a2 = fmaf(w[2][4 * i + 3], h4.w, a2);
        a3 = fmaf(w[3][4 * i + 0], h4.x, a3);
        a3 = fmaf(w[3][4 * i + 1], h4.y, a3);
        a3 = fmaf(w[3][4 * i + 2], h4.z, a3);
        a3 = fmaf(w[3][4 * i + 3], h4.w, a3);
      }
      a0 += (q == 0) ? xg : 0.f;
      a1 += (q == 1) ? xg : 0.f;
      a2 += (q == 2) ? xg : 0.f;
      a3 += (q == 3) ? xg : 0.f;
      a0 += __shfl_xor(a0, 1); a0 += __shfl_xor(a0, 2);
      a1 += __shfl_xor(a1, 1); a1 += __shfl_xor(a1, 2);
      a2 += __shfl_xor(a2, 1); a2 += __shfl_xor(a2, 2);
      a3 += __shfl_xor(a3, 1); a3 += __shfl_xor(a3, 2);
      const float iv = sigm(a0);
      const float fv = sigm(a1);
      const float gv = tanhf_fast(a2);
      const float ov = sigm(a3);
      c = fv * c + iv * gv;
      const float hv = ov * tanhf_fast(c);
      if (q == 0) hl[p ^ 1][jpad] = hv;
      hbuf[u] = hv;
      __syncthreads();
      xg = xgn;
    }
    if (q == 0) {
#pragma unroll
      for (int u = 0; u < 8; u++) {
        const int ss = s8 + u;
        const int tt = dir ? (Tn - 1 - ss) : ss;
        hop[(size_t)tt * 256] = hbuf[u];
      }
    }
  }
  {
    float a0 = 0.f, a1 = 0.f, a2 = 0.f, a3 = 0.f;
    const float* hs = &hl[0][36 * q];
#pragma unroll
    for (int i = 0; i < 8; i++) {
      const float4 h4 = *(const float4*)&hs[4 * i];
      a0 = fmaf(w[0][4 * i + 0], h4.x, a0);
      a0 = fmaf(w[0][4 * i + 1], h4.y, a0);
      a0 = fmaf(w[0][4 * i + 2], h4.z, a0);
      a0 = fmaf(w[0][4 * i + 3], h4.w, a0);
      a1 = fmaf(w[1][4 * i + 0], h4.x, a1);
      a1 = fmaf(w[1][4 * i + 1], h4.y, a1);
      a1 = fmaf(w[1][4 * i + 2], h4.z, a1);
      a1 = fmaf(w[1][4 * i + 3], h4.w, a1);
      a2 = fmaf(w[2][4 * i + 0], h4.x, a2);
      a2 = fmaf(w[2][4 * i + 1], h4.y, a2);
      a2 = fmaf(w[2][4 * i + 2], h4.z, a2);
      a2 = fmaf(w[2][4 * i + 3], h4.w, a2);
      a3 = fmaf(w[3][4 * i + 0], h4.x, a3);
      a3 = fmaf(w[3][4 * i + 1], h4.y, a3);
      a3 = fmaf(w[3][4 * i + 2], h4.z, a3);
      a3 = fmaf(w[3][4 * i + 3], h4.w, a3);
    }
    a0 += (q == 0) ? xg : 0.f;
    a1 += (q == 1) ? xg : 0.f;
    a2 += (q == 2) ? xg : 0.f;
    a3 += (q == 3) ? xg : 0.f;
    a0 += __shfl_xor(a0, 1); a0 += __shfl_xor(a0, 2);
    a1 += __shfl_xor(a1, 1); a1 += __shfl_xor(a1, 2);
    a2 += __shfl_xor(a2, 1); a2 += __shfl_xor(a2, 2);
    a3 += __shfl_xor(a3, 1); a3 += __shfl_xor(a3, 2);
    const float iv = sigm(a0);
    const float fv = sigm(a1);
    const float gv = tanhf_fast(a2);
    const float ov = sigm(a3);
    c = fv * c + iv * gv;
    const float hv = ov * tanhf_fast(c);
    if (q == 0) {
      const int tt = dir ? 0 : (Tn - 1);
      hop[(size_t)tt * 256] = hv;
    }
  }
}

// ---------------------------------------------------------------------------
__global__ __launch_bounds__(256) void dot_v_kernel(
    const float* __restrict__ u, const float* __restrict__ v,
    float* __restrict__ a, int MC)
{
  const int lane = threadIdx.x & 63;
  const int row  = blockIdx.x * 4 + (threadIdx.x >> 6);
  if (row >= MC) return;
  const float4 uv = ((const float4*)(u + (size_t)row * 256))[lane];
  const float4 vv = ((const float4*)v)[lane];
  float p = uv.x * vv.x + uv.y * vv.y + uv.z * vv.z + uv.w * vv.w;
#pragma unroll
  for (int off = 32; off > 0; off >>= 1) p += __shfl_down(p, off);
  if (lane == 0) a[row] = p;
}

// ---------------------------------------------------------------------------
__global__ __launch_bounds__(256) void attn_pool(
    const float* __restrict__ a, const float* __restrict__ h1,
    float* __restrict__ wout)
{
  const int b    = blockIdx.x;
  const int tid  = threadIdx.x;
  const int lane = tid & 63;
  const int wid  = tid >> 6;
  __shared__ float sa[Tn];
  __shared__ float red[8];

  float lmax = -3.4e38f;
  for (int t = tid; t < Tn; t += 256) {
    const float x = a[(size_t)b * Tn + t];
    sa[t] = x;
    lmax  = fmaxf(lmax, x);
  }
#pragma unroll
  for (int off = 1; off < 64; off <<= 1) lmax = fmaxf(lmax, __shfl_xor(lmax, off));
  if (lane == 0) red[wid] = lmax;
  __syncthreads();
  const float bmax = fmaxf(fmaxf(red[0], red[1]), fmaxf(red[2], red[3]));

  float lsum = 0.f;
  for (int t = tid; t < Tn; t += 256) {
    const float e = __expf(sa[t] - bmax);
    sa[t] = e;
    lsum += e;
  }
#pragma unroll
  for (int off = 1; off < 64; off <<= 1) lsum += __shfl_xor(lsum, off);
  if (lane == 0) red[4 + wid] = lsum;
  __syncthreads();
  const float inv = 1.f / (red[4] + red[5] + red[6] + red[7]);

  float acc = 0.f;
  const float* hb = h1 + (size_t)b * Tn * 256 + tid;
  for (int t = 0; t < Tn; t++) acc += sa[t] * hb[(size_t)t * 256];
  wout[(size_t)b * 256 + tid] = acc * inv;
}

// ---------------------------------------------------------------------------
extern "C" void kernel_launch(void* const* d_in, const int* in_sizes, int n_in,
                              void* d_out, int out_size, void* d_ws, size_t ws_size,
                              hipStream_t stream)
{
  const float* X      = (const float*)d_in[0];
  const float* w_ih0f = (const float*)d_in[1];
  const float* w_hh0f = (const float*)d_in[2];
  const float* b_ih0f = (const float*)d_in[3];
  const float* b_hh0f = (const float*)d_in[4];
  const float* w_ih0b = (const float*)d_in[5];
  const float* w_hh0b = (const float*)d_in[6];
  const float* b_ih0b = (const float*)d_in[7];
  const float* b_hh0b = (const float*)d_in[8];
  const float* w_ih1f = (const float*)d_in[9];
  const float* w_hh1f = (const float*)d_in[10];
  const float* b_ih1f = (const float*)d_in[11];
  const float* b_hh1f = (const float*)d_in[12];
  const float* w_ih1b = (const float*)d_in[13];
  const float* w_hh1b = (const float*)d_in[14];
  const float* b_ih1b = (const float*)d_in[15];
  const float* b_hh1b = (const float*)d_in[16];
  const float* att_W  = (const float*)d_in[17];
  const float* att_v  = (const float*)d_in[18];
  const float* head_W = (const float*)d_in[19];
  const float* head_b = (const float*)d_in[20];

  auto al256 = [](size_t x) { return (x + 255) & ~(size_t)255; };

  // footprint for chunk rows mc:
  //   wgt + weight-splits + xwc(2*mc*512 f32) + h0c + h1c + ac + act-region
  auto need_for = [&](size_t mc) -> size_t {
    size_t s = 0;
    s += al256((size_t)512 * 256 * 4);                 // wgt
    s += 4 * al256((size_t)512 * Kp0 * 2);             // w0 f/b hi/lo
    s += 4 * al256((size_t)512 * 256 * 2);             // w1 f/b hi/lo
    s += 2 * al256((size_t)256 * 256 * 2);             // att_W^T hi/lo
    s += al256(2 * mc * (size_t)Gn * 4);               // xwc
    s += al256(mc * 256 * 4);                          // h0c
    s += al256(mc * 256 * 4);                          // h1c
    s += al256(mc * 4);                                // ac
    s += al256(2 * mc * (size_t)Kp0 * 2);              // act split region
    return s;
  };

  int Bc = 8;
  {
    const int cands[7] = {512, 256, 128, 64, 32, 16, 8};
    for (int i = 0; i < 7; i++) {
      if (need_for((size_t)cands[i] * Tn) <= ws_size) { Bc = cands[i]; break; }
    }
  }
  const size_t MCs = (size_t)Bc * Tn;
  const int    MC  = (int)MCs;

  char* p = (char*)d_ws;
  float* wgt  = (float*)p;  p += al256((size_t)512 * 256 * 4);
  u16* w0fh = (u16*)p;      p += al256((size_t)512 * Kp0 * 2);
  u16* w0fl = (u16*)p;      p += al256((size_t)512 * Kp0 * 2);
  u16* w0bh = (u16*)p;      p += al256((size_t)512 * Kp0 * 2);
  u16* w0bl = (u16*)p;      p += al256((size_t)512 * Kp0 * 2);
  u16* w1fh = (u16*)p;      p += al256((size_t)512 * 256 * 2);
  u16* w1fl = (u16*)p;      p += al256((size_t)512 * 256 * 2);
  u16* w1bh = (u16*)p;      p += al256((size_t)512 * 256 * 2);
  u16* w1bl = (u16*)p;      p += al256((size_t)512 * 256 * 2);
  u16* aWh  = (u16*)p;      p += al256((size_t)256 * 256 * 2);
  u16* aWl  = (u16*)p;      p += al256((size_t)256 * 256 * 2);
  float* xwc = (float*)p;   p += al256(2 * MCs * (size_t)Gn * 4);
  float* h0c = (float*)p;   p += al256(MCs * 256 * 4);
  float* h1c = (float*)p;   p += al256(MCs * 256 * 4);
  float* ac  = (float*)p;   p += al256(MCs * 4);
  u16* act_h = (u16*)p;
  u16* act_l = (u16*)(p + MCs * (size_t)Kp0 * 2);      // lo half of act region
  float* u   = xwc;                                    // reuse (xw dead by phase 5)

  const dim3 blk(256);
  const int  mt  = (MC + 127) / 128;
  const int  nch = Bn / Bc;

  // one-time weight splits (K zero-padded to /32; att_W transposed to [N][K])
  split_kernel<0><<<dim3(128), blk, 0, stream>>>(w_ih0f, w0fh, w0fl, 512, Cn, Kp0);
  split_kernel<0><<<dim3(128), blk, 0, stream>>>(w_ih0b, w0bh, w0bl, 512, Cn, Kp0);
  split_kernel<0><<<dim3(128), blk, 0, stream>>>(w_ih1f, w1fh, w1fl, 512, 256, 256);
  split_kernel<0><<<dim3(128), blk, 0, stream>>>(w_ih1b, w1bh, w1bl, 512, 256, 256);
  split_kernel<1><<<dim3(64),  blk, 0, stream>>>(att_W,  aWh,  aWl,  256, 256, 256);

  for (int ch = 0; ch < nch; ch++) {
    const float* Xc   = X + (size_t)ch * Bc * Cn * Tn;
    float*       wgtc = wgt + (size_t)ch * Bc * 256;

    // 0) transpose+split X chunk -> act (bf16 hi/lo, [MC][288])
    xsplit_kernel<<<dim3(9, 9, Bc), blk, 0, stream>>>(Xc, act_h, act_l);
    // 1) layer-0 input projections (MFMA bf16x3), both biases folded
    gemm_mfma3<0, 2><<<dim3(mt, 4), blk, 0, stream>>>(
        act_h, act_l, w0fh, w0fl, b_ih0f, b_hh0f, xwc, MC, Gn, Kp0, Gn);
    gemm_mfma3<0, 2><<<dim3(mt, 4), blk, 0, stream>>>(
        act_h, act_l, w0bh, w0bl, b_ih0b, b_hh0b, xwc + MCs * Gn, MC, Gn, Kp0, Gn);
    // 2) layer-0 recurrence
    lstm_rec3<<<dim3(Bc, 2), dim3(512), 0, stream>>>(xwc, w_hh0f, w_hh0b, h0c, MC);
    // 2.5) split h0 -> act (Xs dead)
    split_kernel<0><<<dim3((MC + 3) / 4), blk, 0, stream>>>(h0c, act_h, act_l, MC, 256, 256);
    // 3) layer-1 input projections
    gemm_mfma3<0, 2><<<dim3(mt, 4), blk, 0, stream>>>(
        act_h, act_l, w1fh, w1fl, b_ih1f, b_hh1f, xwc, MC, Gn, 256, Gn);
    gemm_mfma3<0, 2><<<dim3(mt, 4), blk, 0, stream>>>(
        act_h, act_l, w1bh, w1bl, b_ih1b, b_hh1b, xwc + MCs * Gn, MC, Gn, 256, Gn);
    // 4) layer-1 recurrence
    lstm_rec3<<<dim3(Bc, 2), dim3(512), 0, stream>>>(xwc, w_hh1f, w_hh1b, h1c, MC);
    // 4.5) split h1 -> act (h0s dead)
    split_kernel<0><<<dim3((MC + 3) / 4), blk, 0, stream>>>(h1c, act_h, act_l, MC, 256, 256);
    // 5) u = tanh(h1 @ att_W)
    gemm_mfma3<1, 0><<<dim3(mt, 2), blk, 0, stream>>>(
        act_h, act_l, aWh, aWl, nullptr, nullptr, u, MC, 256, 256, 256);
    // 6) a = u . att_v
    dot_v_kernel<<<dim3((MC + 3) / 4), blk, 0, stream>>>(u, att_v, ac, MC);
    // 7) softmax + pooling into this chunk's wgt slice
    attn_pool<<<dim3(Bc), blk, 0, stream>>>(ac, h1c, wgtc);
  }
  // 8) head (fp32, negligible: 0.5 GFLOP)
  gemm_tile<0, 0, 0, 1><<<dim3((Bn + 127) / 128, (NCLS + 127) / 128), blk, 0, stream>>>(
      wgt, head_W, head_b, nullptr, (float*)d_out, Bn, NCLS, 256, NCLS);
}